// Round 1
// baseline (153.330 us; speedup 1.0000x reference)
//
#include <hip/hip_runtime.h>
#include <math.h>

#define BATCH 16
#define TWIN 8
#define SEQIN 129
#define DMODEL 192
#define GLEN 2048           // TWIN*256
#define NH 24
#define HD 32
#define DS 128
#define NCC 896             // conv channels (x | B); dt handled separately
#define MTOT (BATCH*GLEN)   // 32768
#define NVALID (BATCH*TWIN*128) // 16384 rows with real input (s<128)
#define PADK 104            // GEMM LDS row pitch in bf16 (BK=96 + 8 pad)

typedef __attribute__((ext_vector_type(8))) short bf16x8;
typedef __attribute__((ext_vector_type(4))) float f32x4;

__device__ __forceinline__ float softplus_f(float x){
  return x > 20.f ? x : log1pf(expf(x));
}
__device__ __forceinline__ float silu_f(float x){
  return x / (1.f + __expf(-x));
}
__device__ __forceinline__ unsigned short tobf16(float f){
  union { float f; unsigned u; } v; v.f = f;
  unsigned r = v.u + 0x7FFF + ((v.u >> 16) & 1);
  return (unsigned short)(r >> 16);
}
__device__ __forceinline__ float frombf16(unsigned short u){
  union { unsigned u; float f; } v; v.u = ((unsigned)u) << 16; return v.f;
}
__device__ __forceinline__ bf16x8 pack8(float4 a, float4 b){
  bf16x8 r;
  r[0]=(short)tobf16(a.x); r[1]=(short)tobf16(a.y);
  r[2]=(short)tobf16(a.z); r[3]=(short)tobf16(a.w);
  r[4]=(short)tobf16(b.x); r[5]=(short)tobf16(b.y);
  r[6]=(short)tobf16(b.z); r[7]=(short)tobf16(b.w);
  return r;
}

// k_build: vectorized input cast (768) + bf16 weight copy (84) + ptab (64)
// + compact dt GEMM (256). 1172 blocks total.
__global__ __launch_bounds__(256) void k_build(const float* __restrict__ in,
    const float* __restrict__ inw, unsigned short* __restrict__ inh,
    unsigned short* __restrict__ wh, float* __restrict__ ptab,
    float* __restrict__ dtraw){
  __shared__ float smem[2048];
  int bx = blockIdx.x;
  int tid = threadIdx.x;
  if (bx < 768){
    int idx = (bx*256 + tid)*16;      // < NVALID*DMODEL exactly
    int v = idx / DMODEL;             // compact row: bt*128 + s
    int d = idx - v*DMODEL;
    int bt = v >> 7, s = v & 127;
    const float* src = in + ((size_t)bt*SEQIN + s + 1)*DMODEL + d;
    float4 a0 = *(const float4*)src;
    float4 a1 = *(const float4*)(src+4);
    float4 a2 = *(const float4*)(src+8);
    float4 a3 = *(const float4*)(src+12);
    *(bf16x8*)&inh[idx]   = pack8(a0, a1);
    *(bf16x8*)&inh[idx+8] = pack8(a2, a3);
  } else if (bx < 852){
    int idx = ((bx-768)*256 + tid)*8;  // < NCC*DMODEL exactly
    const float* src = inw + (size_t)768*DMODEL + idx;
    float4 a = *(const float4*)src;
    float4 b = *(const float4*)(src+4);
    *(bf16x8*)&wh[idx] = pack8(a, b);
  } else if (bx < 916){
    // ptab[t][e] = sum_d PE[t][d]*W[row(e)][d]  (fp32)
    float* pe = smem;
    int pb = bx - 852;            // 0..63
    int t = pb >> 3, eslice = pb & 7;
    if (tid < DMODEL){
      int d = tid;
      float div = expf(-(float)(d & ~1) * (logf(10000.f)/(float)DMODEL));
      float ang = (float)t * div;
      pe[d] = (d & 1) ? cosf(ang) : sinf(ang);
    }
    __syncthreads();
    int e0 = eslice*115;
    int e1 = min(920, e0 + 115);
    for (int e = e0 + tid; e < e1; e += 256){
      int row = (e < 896) ? (768 + e) : (1792 + (e - 896));
      const float* wr = inw + (size_t)row*DMODEL;
      float s = 0.f;
      #pragma unroll 4
      for (int d = 0; d < DMODEL; d++)
        s += pe[d] * wr[d];
      ptab[t*920 + e] = s;
    }
  } else {
    // fp32 GEMM for 24 dt channels, compact rows
    float* As = smem;          // [16][64]
    float* Bs = smem + 1024;
    int idx = bx - 916;                // 0..255
    int m0 = idx*64;
    int bt = m0 >> 7, srow = m0 & 127;
    int ty = tid >> 4, tx = tid & 15;
    int lr = tid >> 2, lq = tid & 3;
    float acc[4][4] = {};
    for (int k0 = 0; k0 < DMODEL; k0 += 16){
      float4 av = *(const float4*)(in + ((size_t)bt*SEQIN + srow + 1 + lr)*DMODEL + k0 + lq*4);
      As[(lq*4+0)*64+lr] = av.x; As[(lq*4+1)*64+lr] = av.y;
      As[(lq*4+2)*64+lr] = av.z; As[(lq*4+3)*64+lr] = av.w;
      float4 bv = make_float4(0.f,0.f,0.f,0.f);
      if (lr < NH) bv = *(const float4*)(inw + (size_t)(1792+lr)*DMODEL + k0 + lq*4);
      Bs[(lq*4+0)*64+lr] = bv.x; Bs[(lq*4+1)*64+lr] = bv.y;
      Bs[(lq*4+2)*64+lr] = bv.z; Bs[(lq*4+3)*64+lr] = bv.w;
      __syncthreads();
      #pragma unroll
      for (int kk = 0; kk < 16; kk++){
        float4 a = *(const float4*)&As[kk*64 + ty*4];
        float4 bq = *(const float4*)&Bs[kk*64 + tx*4];
        float avr[4] = {a.x, a.y, a.z, a.w};
        float bvr[4] = {bq.x, bq.y, bq.z, bq.w};
        #pragma unroll
        for (int i=0;i<4;i++)
          #pragma unroll
          for (int j=0;j<4;j++)
            acc[i][j] += avr[i]*bvr[j];
      }
      __syncthreads();
    }
    #pragma unroll
    for (int i=0;i<4;i++){
      int m = m0 + ty*4 + i;
      #pragma unroll
      for (int j=0;j<4;j++){
        int n = tx*4 + j;
        if (n < NH) dtraw[(size_t)m*NH + n] = acc[i][j];
      }
    }
  }
}

// Fused: bf16 MFMA GEMM on compact inh (+ptab epilogue + pad rows 128..135)
// + scan_w. Grid: 896 GEMM + 384 scan = 1280 blocks.
// BK=96: 2 K-phases, 4 barriers/block (was 6 phases / 12 barriers).
__global__ __launch_bounds__(256) void k_gemmall(const unsigned short* __restrict__ inh,
    const unsigned short* __restrict__ wh, const float* __restrict__ ptab,
    const float* __restrict__ dtraw, const float* __restrict__ dt_bias,
    const float* __restrict__ A_log, unsigned short* __restrict__ projh,
    float* __restrict__ wbuf, float* __restrict__ wsum){
  __shared__ char smem[53248];
  int bx = blockIdx.x;
  int tid = threadIdx.x;
  if (bx < 896){
    unsigned short* As = (unsigned short*)smem;        // [128][PADK]
    unsigned short* Bs = As + 128*PADK;                // [128][PADK]
    int mt = bx & 127;              // compact tile = bt index
    int n0 = (bx >> 7)*128;
    int t = mt & 7;
    size_t msrc = (size_t)mt*128;
    size_t mdst = (size_t)(mt >> 3)*GLEN + (size_t)t*256;
    int wid = tid >> 6, lane = tid & 63;
    int wm = (wid >> 1)*64, wn = (wid & 1)*64;
    int quad = lane >> 4, lm = lane & 15;
    int sr = tid >> 2, sq = tid & 3;
    f32x4 acc[4][4];
    #pragma unroll
    for (int i=0;i<4;i++)
      #pragma unroll
      for (int j=0;j<4;j++) acc[i][j] = (f32x4){0.f,0.f,0.f,0.f};
    for (int k0 = 0; k0 < DMODEL; k0 += 96){
      #pragma unroll
      for (int kk = 0; kk < 96; kk += 32){
        #pragma unroll
        for (int half=0; half<2; half++){
          int r = sr + half*64;
          *(bf16x8*)&As[r*PADK + kk + sq*8] =
            *(const bf16x8*)&inh[(msrc + r)*DMODEL + k0 + kk + sq*8];
          *(bf16x8*)&Bs[r*PADK + kk + sq*8] =
            *(const bf16x8*)&wh[(size_t)(n0+r)*DMODEL + k0 + kk + sq*8];
        }
      }
      __syncthreads();
      #pragma unroll
      for (int kk = 0; kk < 3; kk++){
        bf16x8 aF[4], bF[4];
        #pragma unroll
        for (int i=0;i<4;i++){
          aF[i] = *(const bf16x8*)&As[(wm + i*16 + lm)*PADK + kk*32 + quad*8];
          bF[i] = *(const bf16x8*)&Bs[(wn + i*16 + lm)*PADK + kk*32 + quad*8];
        }
        #pragma unroll
        for (int i=0;i<4;i++)
          #pragma unroll
          for (int j=0;j<4;j++)
            acc[i][j] = __builtin_amdgcn_mfma_f32_16x16x32_bf16(aF[i], bF[j], acc[i][j], 0,0,0);
      }
      __syncthreads();
    }
    float ptn[4];
    #pragma unroll
    for (int j=0;j<4;j++) ptn[j] = ptab[t*920 + n0 + wn + lm + j*16];
    #pragma unroll
    for (int i=0;i<4;i++){
      #pragma unroll
      for (int r=0;r<4;r++){
        int m = wm + i*16 + quad*4 + r;
        unsigned short* dst = projh + (mdst + m)*NCC + n0 + wn + lm;
        #pragma unroll
        for (int j=0;j<4;j++)
          dst[j*16] = tobf16(acc[i][j][r] + ptn[j]);
      }
    }
    // pad rows 128..135 for this n-slice (const bf16(ptab) values;
    // rows 253..255 no longer materialized — consumers read ptab directly)
    {
      int r = tid >> 5;            // 0..7
      int c4 = (tid & 31)*4;       // 0..124
      float4 pv = *(const float4*)&ptab[t*920 + n0 + c4];
      ushort4 v;
      v.x = tobf16(pv.x); v.y = tobf16(pv.y);
      v.z = tobf16(pv.z); v.w = tobf16(pv.w);
      *(ushort4*)&projh[(mdst + 128 + r)*NCC + n0 + c4] = v;
    }
  } else {
    // scan_w: per (b,h) decay weights + const-tail sums
    float* wtot = (float*)smem;        // 4
    float* sred = (float*)smem + 4;    // 256
    int idx = bx - 896;                // 0..383
    int h = idx % NH, b = idx / NH;
    int lane = tid & 63, wid = tid >> 6;
    int tw = tid >> 5, q = tid & 31;
    float dtb = dt_bias[h];
    float negA = -expf(A_log[h]);
    float off = ptab[tw*920 + 896 + h] + dtb;
    float dtv[8], pre[8];
    float run = 0.f;
    if (q < 16){
      size_t rb = ((size_t)(b*TWIN + tw)*128 + q*8)*NH + h;
      #pragma unroll
      for (int i=0;i<8;i++){
        float dt = softplus_f(dtraw[rb + (size_t)i*NH] + off);
        run += dt * negA;
        dtv[i] = dt; pre[i] = run;
      }
    } else {
      float dt = softplus_f(off);
      #pragma unroll
      for (int i=0;i<8;i++){
        run += dt * negA;
        dtv[i] = dt; pre[i] = run;
      }
    }
    float v = run;
    #pragma unroll
    for (int o=1; o<64; o<<=1){
      float u = __shfl_up(v, o, 64);
      if (lane >= o) v += u;
    }
    if (lane == 63) wtot[wid] = v;
    __syncthreads();
    float base = 0.f, total = 0.f;
    #pragma unroll
    for (int w2=0; w2<4; w2++){
      float tv = wtot[w2];
      if (w2 < wid) base += tv;
      total += tv;
    }
    float excl = base + v - run;
    float ls = 0.f;
    size_t gb = (size_t)b*GLEN + tw*256 + q*8;
    #pragma unroll
    for (int i=0;i<8;i++){
      float w = expf(total - (excl + pre[i])) * dtv[i];
      if (q < 17) wbuf[(gb + i)*NH + h] = w;
      else ls += w;
    }
    sred[tid] = ls;
    __syncthreads();
    if (q == 17){
      float acc = ls;
      for (int r = 18; r < 32; r++) acc += sred[tw*32 + r];
      wsum[((size_t)b*TWIN + tw)*NH + h] = acc;
    }
  }
}

// Fused: fold+partial (512 blocks: (bt,sub), 34 positions each, full 136
// coverage) + const-tail rows (128) + boundary vectors (112). 752 blocks.
__global__ __launch_bounds__(256) void k_foldall(const unsigned short* __restrict__ projh,
    const float* __restrict__ conv_w, const float* __restrict__ conv_b,
    const float* __restrict__ wbuf, const float* __restrict__ ptab,
    const float* __restrict__ wsum, float* __restrict__ partial,
    float* __restrict__ cB, float* __restrict__ cbuf){
  __shared__ float smem[5440];   // 34*160 ybuf (branch A) / 2800 (B,C)
  int bx = blockIdx.x;
  int tid = threadIdx.x;
  if (bx < 512){
    // fold+partial: block = (bt, sub); waves fold 9 positions each at starts
    // {0,9,17,25} (position 25 duplicated with identical data — benign).
    int bt = bx >> 2, sub = bx & 3;
    int b = bt >> 3, t = bt & 7;
    int wave = tid >> 6, lane = tid & 63;
    int g0 = t*256 + sub*34;
    int wstart = wave*8 + (wave > 0 ? 1 : 0);   // 0,9,17,25
    int gw = g0 + wstart;
    size_t rbase = (size_t)b*GLEN;
    float* ybuf = smem;
    float cb[7][2], cw[7][2][4];
    #pragma unroll
    for (int k=0;k<7;k++){
      int c = 2*lane + 128*k;
      float2 tb = *(const float2*)&conv_b[c];
      cb[k][0]=tb.x; cb[k][1]=tb.y;
      float4 w0 = *(const float4*)&conv_w[c*4];
      float4 w1 = *(const float4*)&conv_w[(c+1)*4];
      cw[k][0][0]=w0.x; cw[k][0][1]=w0.y; cw[k][0][2]=w0.z; cw[k][0][3]=w0.w;
      cw[k][1][0]=w1.x; cw[k][1][1]=w1.y; cw[k][1][2]=w1.z; cw[k][1][3]=w1.w;
    }
    float h0[7][2], h1[7][2], h2[7][2];
    #pragma unroll
    for (int k=0;k<7;k++){
      h0[k][0]=h0[k][1]=h1[k][0]=h1[k][1]=h2[k][0]=h2[k][1]=0.f;
    }
    if (gw >= 3){
      if ((gw & 255) == 0){
        // chunk start (t>=1): history = prev chunk pad rows = const bf16(ptab[t-1])
        int tp = (gw >> 8) - 1;
        #pragma unroll
        for (int k=0;k<7;k++){
          int c = 2*lane + 128*k;
          float v0 = frombf16(tobf16(ptab[tp*920 + c]));
          float v1 = frombf16(tobf16(ptab[tp*920 + c + 1]));
          h0[k][0]=v0; h0[k][1]=v1;
          h1[k][0]=v0; h1[k][1]=v1;
          h2[k][0]=v0; h2[k][1]=v1;
        }
      } else {
        #pragma unroll
        for (int k=0;k<7;k++){
          int c = 2*lane + 128*k;
          ushort2 p0 = *(const ushort2*)&projh[(rbase+gw-3)*NCC + c];
          ushort2 p1 = *(const ushort2*)&projh[(rbase+gw-2)*NCC + c];
          ushort2 p2 = *(const ushort2*)&projh[(rbase+gw-1)*NCC + c];
          h0[k][0]=frombf16(p0.x); h0[k][1]=frombf16(p0.y);
          h1[k][0]=frombf16(p1.x); h1[k][1]=frombf16(p1.y);
          h2[k][0]=frombf16(p2.x); h2[k][1]=frombf16(p2.y);
        }
      }
    }
    #pragma unroll
    for (int i=0;i<9;i++){
      size_t row = rbase + gw + i;
      float wreg = (lane < NH) ? wbuf[row*NH + lane] : 0.f;
      float cur[7][2];
      #pragma unroll
      for (int k=0;k<7;k++){
        int c = 2*lane + 128*k;
        ushort2 pv = *(const ushort2*)&projh[row*NCC + c];
        cur[k][0]=frombf16(pv.x); cur[k][1]=frombf16(pv.y);
      }
      float py0=0.f, py1=0.f, b0v=0.f, b1v=0.f;
      #pragma unroll
      for (int k=0;k<7;k++){
        float a0 = cb[k][0] + h0[k][0]*cw[k][0][0] + h1[k][0]*cw[k][0][1]
                            + h2[k][0]*cw[k][0][2] + cur[k][0]*cw[k][0][3];
        float a1 = cb[k][1] + h0[k][1]*cw[k][1][0] + h1[k][1]*cw[k][1][1]
                            + h2[k][1]*cw[k][1][2] + cur[k][1]*cw[k][1][3];
        float s0 = silu_f(a0), s1 = silu_f(a1);
        if (k < 6){
          float wh_ = __shfl(wreg, (lane>>4) + 4*k, 64);
          py0 += wh_*s0; py1 += wh_*s1;
        } else { b0v = s0; b1v = s1; }
      }
      py0 += __shfl_xor(py0, 16, 64); py0 += __shfl_xor(py0, 32, 64);
      py1 += __shfl_xor(py1, 16, 64); py1 += __shfl_xor(py1, 32, 64);
      float* dst = ybuf + (wstart + i)*160;
      if (lane < 16) *(float2*)&dst[2*lane] = make_float2(py0, py1);
      *(float2*)&dst[32 + 2*lane] = make_float2(b0v, b1v);
      #pragma unroll
      for (int k=0;k<7;k++){
        h0[k][0]=h1[k][0]; h0[k][1]=h1[k][1];
        h1[k][0]=h2[k][0]; h1[k][1]=h2[k][1];
        h2[k][0]=cur[k][0]; h2[k][1]=cur[k][1];
      }
    }
    __syncthreads();
    int p0 = (tid >> 5)*4, n0 = (tid & 31)*4;
    float acc[4][4] = {};
    #pragma unroll 2
    for (int gi = 0; gi < 34; gi++){
      float4 yv = *(const float4*)&ybuf[gi*160 + p0];
      float4 bv = *(const float4*)&ybuf[gi*160 + 32 + n0];
      float ya[4] = {yv.x,yv.y,yv.z,yv.w};
      float ba[4] = {bv.x,bv.y,bv.z,bv.w};
      #pragma unroll
      for (int i=0;i<4;i++)
        #pragma unroll
        for (int j=0;j<4;j++)
          acc[i][j] += ya[i]*ba[j];
    }
    size_t pb = ((size_t)bt*4 + sub)*4096;
    #pragma unroll
    for (int i=0;i<4;i++)
      #pragma unroll
      for (int j=0;j<4;j++)
        partial[pb + (p0+i)*128 + n0+j] = acc[i][j];
  } else if (bx < 640){
    float* Xc = smem;            // 896
    float* Ws = smem + 896;      // 24
    int idx = bx - 512;
    int t = idx & 7, b = idx >> 3;
    for (int c = tid; c < NCC; c += 256){
      float4 w = *(const float4*)&conv_w[c*4];
      float sw = w.x + w.y + w.z + w.w;
      float a = conv_b[c] + frombf16(tobf16(ptab[t*920 + c])) * sw;
      Xc[c] = silu_f(a);
    }
    if (tid < NH) Ws[tid] = wsum[((size_t)b*TWIN + t)*NH + tid];
    __syncthreads();
    float* dst = cB + ((size_t)(b*TWIN + t))*160;
    if (tid < 32){
      float y = 0.f;
      #pragma unroll
      for (int h=0;h<NH;h++) y += Ws[h]*Xc[h*32 + tid];
      dst[tid] = y;
    } else if (tid < 160){
      dst[tid] = Xc[768 + tid - 32];
    }
  } else {
    float* xsw  = smem;          // 896
    float* xsg  = smem + 896;    // 896
    float* wv   = smem + 1792;   // 24
    float* bufw = smem + 1816;   // 480
    float* bufg = smem + 2296;   // 480
    int idx = bx - 640;          // 0..111
    int b = idx / 7, t = idx % 7 + 1;
    size_t rbase = (size_t)b*GLEN;
    int g0 = t*256;
    for (int gi=0; gi<3; gi++){
      int g = g0 + gi;
      if (tid < NH) wv[tid] = wbuf[(rbase+g)*NH + tid];
      for (int c = tid; c < NCC; c += 256){
        float aw = conv_b[c], ag = conv_b[c];
        #pragma unroll
        for (int k=0;k<4;k++){
          int gp = g - 3 + k;
          // gp < g0: prev chunk pad row = const bf16(ptab[t-1])
          float pj = (gp >= g0) ? frombf16(projh[(rbase+gp)*NCC + c])
                                : frombf16(tobf16(ptab[(t-1)*920 + c]));
          float term = pj * conv_w[c*4+k];
          ag += term;
          if (gp >= g0) aw += term;
        }
        xsw[c] = silu_f(aw);
        xsg[c] = silu_f(ag);
      }
      __syncthreads();
      if (tid < 32){
        float yw = 0.f, yg = 0.f;
        #pragma unroll
        for (int h=0;h<NH;h++){ yw += wv[h]*xsw[h*32+tid]; yg += wv[h]*xsg[h*32+tid]; }
        bufw[gi*160 + tid] = yw;
        bufg[gi*160 + tid] = yg;
      } else if (tid < 160){
        bufw[gi*160 + tid] = xsw[768 + tid - 32];
        bufg[gi*160 + tid] = xsg[768 + tid - 32];
      }
      __syncthreads();
    }
    float* dst = cbuf + ((size_t)(b*TWIN + t))*960;
    for (int i = tid; i < 960; i += 256){
      int gi = i / 320, rem = i - gi*320;
      dst[i] = (rem < 160) ? bufw[gi*160 + rem] : bufg[gi*160 + rem - 160];
    }
  }
}

// Suffix-sum + const-tail + inline boundary deltas.
__global__ __launch_bounds__(256) void k_suffix(const float* __restrict__ partial,
    const float* __restrict__ cB, const float* __restrict__ cbuf,
    float* __restrict__ feat){
  int b = blockIdx.y;
  int e = blockIdx.x*256 + threadIdx.x;   // 0..4095
  int p = e >> 7, n = e & 127;
  float s = 0.f;
  for (int t = TWIN-1; t >= 0; t--){
    int bt = b*TWIN + t;
    size_t pb = (size_t)bt*4*4096;
    s += partial[pb + e] + partial[pb + 4096 + e]
       + partial[pb + 2*4096 + e] + partial[pb + 3*4096 + e];
    const float* cb_ = cB + (size_t)bt*160;
    s += cb_[p] * cb_[32 + n];
    float f = s;
    if (t > 0){
      const float* cw_ = cbuf + (size_t)bt*960;
      #pragma unroll
      for (int gi=0; gi<3; gi++){
        const float* rw = cw_ + gi*320;
        f += rw[p]*rw[32+n] - rw[160+p]*rw[192+n];
      }
    }
    feat[(size_t)bt*4096 + e] = f;
  }
}

// Classifier: 4x8 register-tiled, grid (32 bt-quads, 13 k-octs).
__global__ __launch_bounds__(256) void k_classifier(const float* __restrict__ feat,
    const float* __restrict__ cls_w, const float* __restrict__ cls_b,
    float* __restrict__ out){
  int bt0 = blockIdx.x*4;
  int k0  = blockIdx.y*8;
  int tid = threadIdx.x, wid = tid >> 6, lane = tid & 63;
  float acc[4][8] = {};
  int j0 = wid*1024;
  #pragma unroll
  for (int it = 0; it < 4; it++){
    int j = j0 + it*256 + lane*4;
    float4 f4[4], w4[8];
    #pragma unroll
    for (int i=0;i<4;i++) f4[i] = *(const float4*)(feat + (size_t)(bt0+i)*4096 + j);
    #pragma unroll
    for (int k=0;k<8;k++){
      int kr = k0 + k; kr = kr < 100 ? kr : 99;
      w4[k] = *(const float4*)(cls_w + (size_t)kr*4096 + j);
    }
    #pragma unroll
    for (int i=0;i<4;i++)
      #pragma unroll
      for (int k=0;k<8;k++)
        acc[i][k] += f4[i].x*w4[k].x + f4[i].y*w4[k].y
                   + f4[i].z*w4[k].z + f4[i].w*w4[k].w;
  }
  #pragma unroll
  for (int i=0;i<4;i++)
    #pragma unroll
    for (int k=0;k<8;k++)
      #pragma unroll
      for (int o=32; o>0; o>>=1)
        acc[i][k] += __shfl_down(acc[i][k], o, 64);
  __shared__ float part[4][32];
  if (lane == 0){
    #pragma unroll
    for (int i=0;i<4;i++)
      #pragma unroll
      for (int k=0;k<8;k++)
        part[wid][i*8+k] = acc[i][k];
  }
  __syncthreads();
  if (tid < 32){
    int i = tid >> 3, k = tid & 7;
    float s = part[0][tid] + part[1][tid] + part[2][tid] + part[3][tid];
    int kr = k0 + k;
    if (kr < 100) out[(size_t)(bt0+i)*100 + kr] = s + cls_b[kr];
  }
}

extern "C" void kernel_launch(void* const* d_in, const int* in_sizes, int n_in,
                              void* d_out, int out_size, void* d_ws, size_t ws_size,
                              hipStream_t stream){
  const float* inputs    = (const float*)d_in[0];
  const float* in_proj_w = (const float*)d_in[1];
  const float* conv_w    = (const float*)d_in[2];
  const float* conv_b    = (const float*)d_in[3];
  const float* dt_bias   = (const float*)d_in[4];
  const float* A_log     = (const float*)d_in[5];
  const float* cls_w     = (const float*)d_in[6];
  const float* cls_b     = (const float*)d_in[7];
  float* out = (float*)d_out;

  unsigned short* projh= (unsigned short*)d_ws;                 // MTOT*896 bf16
  float* dtraw         = (float*)(projh + (size_t)MTOT*NCC);    // NVALID*24 f32 (compact)
  float* wbuf          = dtraw + (size_t)NVALID*NH;             // MTOT*24 f32
  unsigned short* inh  = (unsigned short*)(wbuf + (size_t)MTOT*NH); // NVALID*192 bf16
  unsigned short* wh   = inh + (size_t)NVALID*DMODEL;           // NCC*192 bf16
  float* partial       = (float*)(wh + (size_t)NCC*DMODEL);     // 512*4096 f32
  float* feat          = partial + (size_t)512*4096;            // 128*4096 f32
  float* ptab          = feat + (size_t)128*4096;               // 8*920 f32
  float* wsum          = ptab + (size_t)8*920;                  // 128*24 f32
  float* cB            = wsum + (size_t)128*NH;                 // 128*160 f32
  float* cbuf          = cB + (size_t)128*160;                  // 128*960 f32
  size_t need = (size_t)((char*)(cbuf + (size_t)128*960) - (char*)d_ws);
  if (ws_size < need) return;

  k_build      <<<1172, 256, 0, stream>>>(inputs, in_proj_w, inh, wh, ptab, dtraw);
  k_gemmall    <<<1280, 256, 0, stream>>>(inh, wh, ptab, dtraw, dt_bias, A_log,
                                          projh, wbuf, wsum);
  k_foldall    <<<752, 256, 0, stream>>>(projh, conv_w, conv_b, wbuf, ptab, wsum,
                                         partial, cB, cbuf);
  k_suffix     <<<dim3(16, BATCH), 256, 0, stream>>>(partial, cB, cbuf, feat);
  k_classifier <<<dim3(32, 13), 256, 0, stream>>>(feat, cls_w, cls_b, out);
}

// Round 2
// 152.260 us; speedup vs baseline: 1.0070x; 1.0070x over previous
//
#include <hip/hip_runtime.h>
#include <math.h>

#define BATCH 16
#define TWIN 8
#define SEQIN 129
#define DMODEL 192
#define GLEN 2048           // TWIN*256
#define NH 24
#define HD 32
#define DS 128
#define NCC 896             // conv channels (x | B); dt handled separately
#define MTOT (BATCH*GLEN)   // 32768
#define NVALID (BATCH*TWIN*128) // 16384 rows with real input (s<128)
#define PADK 104            // GEMM LDS row pitch in bf16 (BK=96 + 8 pad)

typedef __attribute__((ext_vector_type(8))) short bf16x8;
typedef __attribute__((ext_vector_type(4))) float f32x4;

__device__ __forceinline__ float softplus_f(float x){
  return x > 20.f ? x : log1pf(expf(x));
}
__device__ __forceinline__ float silu_f(float x){
  return x / (1.f + __expf(-x));
}
__device__ __forceinline__ unsigned short tobf16(float f){
  union { float f; unsigned u; } v; v.f = f;
  unsigned r = v.u + 0x7FFF + ((v.u >> 16) & 1);
  return (unsigned short)(r >> 16);
}
__device__ __forceinline__ float frombf16(unsigned short u){
  union { unsigned u; float f; } v; v.u = ((unsigned)u) << 16; return v.f;
}
// packed bf16 pair (low ushort = channel c, high ushort = channel c+1)
__device__ __forceinline__ float bflo(unsigned u){
  union { unsigned x; float f; } v; v.x = u << 16; return v.f;
}
__device__ __forceinline__ float bfhi(unsigned u){
  union { unsigned x; float f; } v; v.x = u & 0xffff0000u; return v.f;
}
__device__ __forceinline__ bf16x8 pack8(float4 a, float4 b){
  bf16x8 r;
  r[0]=(short)tobf16(a.x); r[1]=(short)tobf16(a.y);
  r[2]=(short)tobf16(a.z); r[3]=(short)tobf16(a.w);
  r[4]=(short)tobf16(b.x); r[5]=(short)tobf16(b.y);
  r[6]=(short)tobf16(b.z); r[7]=(short)tobf16(b.w);
  return r;
}

// k_build: vectorized input cast (768) + bf16 weight copy (84) + ptab (64)
// + compact dt GEMM (256). 1172 blocks total.
__global__ __launch_bounds__(256) void k_build(const float* __restrict__ in,
    const float* __restrict__ inw, unsigned short* __restrict__ inh,
    unsigned short* __restrict__ wh, float* __restrict__ ptab,
    float* __restrict__ dtraw){
  __shared__ float smem[2048];
  int bx = blockIdx.x;
  int tid = threadIdx.x;
  if (bx < 768){
    int idx = (bx*256 + tid)*16;      // < NVALID*DMODEL exactly
    int v = idx / DMODEL;             // compact row: bt*128 + s
    int d = idx - v*DMODEL;
    int bt = v >> 7, s = v & 127;
    const float* src = in + ((size_t)bt*SEQIN + s + 1)*DMODEL + d;
    float4 a0 = *(const float4*)src;
    float4 a1 = *(const float4*)(src+4);
    float4 a2 = *(const float4*)(src+8);
    float4 a3 = *(const float4*)(src+12);
    *(bf16x8*)&inh[idx]   = pack8(a0, a1);
    *(bf16x8*)&inh[idx+8] = pack8(a2, a3);
  } else if (bx < 852){
    int idx = ((bx-768)*256 + tid)*8;  // < NCC*DMODEL exactly
    const float* src = inw + (size_t)768*DMODEL + idx;
    float4 a = *(const float4*)src;
    float4 b = *(const float4*)(src+4);
    *(bf16x8*)&wh[idx] = pack8(a, b);
  } else if (bx < 916){
    // ptab[t][e] = sum_d PE[t][d]*W[row(e)][d]  (fp32)
    float* pe = smem;
    int pb = bx - 852;            // 0..63
    int t = pb >> 3, eslice = pb & 7;
    if (tid < DMODEL){
      int d = tid;
      float div = expf(-(float)(d & ~1) * (logf(10000.f)/(float)DMODEL));
      float ang = (float)t * div;
      pe[d] = (d & 1) ? cosf(ang) : sinf(ang);
    }
    __syncthreads();
    int e0 = eslice*115;
    int e1 = min(920, e0 + 115);
    for (int e = e0 + tid; e < e1; e += 256){
      int row = (e < 896) ? (768 + e) : (1792 + (e - 896));
      const float* wr = inw + (size_t)row*DMODEL;
      float s = 0.f;
      #pragma unroll 4
      for (int d = 0; d < DMODEL; d++)
        s += pe[d] * wr[d];
      ptab[t*920 + e] = s;
    }
  } else {
    // fp32 GEMM for 24 dt channels, compact rows
    float* As = smem;          // [16][64]
    float* Bs = smem + 1024;
    int idx = bx - 916;                // 0..255
    int m0 = idx*64;
    int bt = m0 >> 7, srow = m0 & 127;
    int ty = tid >> 4, tx = tid & 15;
    int lr = tid >> 2, lq = tid & 3;
    float acc[4][4] = {};
    for (int k0 = 0; k0 < DMODEL; k0 += 16){
      float4 av = *(const float4*)(in + ((size_t)bt*SEQIN + srow + 1 + lr)*DMODEL + k0 + lq*4);
      As[(lq*4+0)*64+lr] = av.x; As[(lq*4+1)*64+lr] = av.y;
      As[(lq*4+2)*64+lr] = av.z; As[(lq*4+3)*64+lr] = av.w;
      float4 bv = make_float4(0.f,0.f,0.f,0.f);
      if (lr < NH) bv = *(const float4*)(inw + (size_t)(1792+lr)*DMODEL + k0 + lq*4);
      Bs[(lq*4+0)*64+lr] = bv.x; Bs[(lq*4+1)*64+lr] = bv.y;
      Bs[(lq*4+2)*64+lr] = bv.z; Bs[(lq*4+3)*64+lr] = bv.w;
      __syncthreads();
      #pragma unroll
      for (int kk = 0; kk < 16; kk++){
        float4 a = *(const float4*)&As[kk*64 + ty*4];
        float4 bq = *(const float4*)&Bs[kk*64 + tx*4];
        float avr[4] = {a.x, a.y, a.z, a.w};
        float bvr[4] = {bq.x, bq.y, bq.z, bq.w};
        #pragma unroll
        for (int i=0;i<4;i++)
          #pragma unroll
          for (int j=0;j<4;j++)
            acc[i][j] += avr[i]*bvr[j];
      }
      __syncthreads();
    }
    #pragma unroll
    for (int i=0;i<4;i++){
      int m = m0 + ty*4 + i;
      #pragma unroll
      for (int j=0;j<4;j++){
        int n = tx*4 + j;
        if (n < NH) dtraw[(size_t)m*NH + n] = acc[i][j];
      }
    }
  }
}

// Fused: bf16 MFMA GEMM on compact inh (+ptab epilogue + pad rows 128..135
// and 253..255) + scan_w. Grid: 896 GEMM + 384 scan = 1280 blocks.
__global__ __launch_bounds__(256) void k_gemmall(const unsigned short* __restrict__ inh,
    const unsigned short* __restrict__ wh, const float* __restrict__ ptab,
    const float* __restrict__ dtraw, const float* __restrict__ dt_bias,
    const float* __restrict__ A_log, unsigned short* __restrict__ projh,
    float* __restrict__ wbuf, float* __restrict__ wsum){
  __shared__ char smem[53248];
  int bx = blockIdx.x;
  int tid = threadIdx.x;
  if (bx < 896){
    unsigned short* As = (unsigned short*)smem;        // [128][PADK]
    unsigned short* Bs = As + 128*PADK;                // [128][PADK]
    int mt = bx & 127;              // compact tile = bt index
    int n0 = (bx >> 7)*128;
    int t = mt & 7;
    size_t msrc = (size_t)mt*128;
    size_t mdst = (size_t)(mt >> 3)*GLEN + (size_t)t*256;
    int wid = tid >> 6, lane = tid & 63;
    int wm = (wid >> 1)*64, wn = (wid & 1)*64;
    int quad = lane >> 4, lm = lane & 15;
    int sr = tid >> 2, sq = tid & 3;
    f32x4 acc[4][4];
    #pragma unroll
    for (int i=0;i<4;i++)
      #pragma unroll
      for (int j=0;j<4;j++) acc[i][j] = (f32x4){0.f,0.f,0.f,0.f};
    for (int k0 = 0; k0 < DMODEL; k0 += 96){
      #pragma unroll
      for (int kk = 0; kk < 96; kk += 32){
        #pragma unroll
        for (int half=0; half<2; half++){
          int r = sr + half*64;
          *(bf16x8*)&As[r*PADK + kk + sq*8] =
            *(const bf16x8*)&inh[(msrc + r)*DMODEL + k0 + kk + sq*8];
          *(bf16x8*)&Bs[r*PADK + kk + sq*8] =
            *(const bf16x8*)&wh[(size_t)(n0+r)*DMODEL + k0 + kk + sq*8];
        }
      }
      __syncthreads();
      #pragma unroll
      for (int kk = 0; kk < 3; kk++){
        bf16x8 aF[4], bF[4];
        #pragma unroll
        for (int i=0;i<4;i++){
          aF[i] = *(const bf16x8*)&As[(wm + i*16 + lm)*PADK + kk*32 + quad*8];
          bF[i] = *(const bf16x8*)&Bs[(wn + i*16 + lm)*PADK + kk*32 + quad*8];
        }
        #pragma unroll
        for (int i=0;i<4;i++)
          #pragma unroll
          for (int j=0;j<4;j++)
            acc[i][j] = __builtin_amdgcn_mfma_f32_16x16x32_bf16(aF[i], bF[j], acc[i][j], 0,0,0);
      }
      __syncthreads();
    }
    float ptn[4];
    #pragma unroll
    for (int j=0;j<4;j++) ptn[j] = ptab[t*920 + n0 + wn + lm + j*16];
    #pragma unroll
    for (int i=0;i<4;i++){
      #pragma unroll
      for (int r=0;r<4;r++){
        int m = wm + i*16 + quad*4 + r;
        unsigned short* dst = projh + (mdst + m)*NCC + n0 + wn + lm;
        #pragma unroll
        for (int j=0;j<4;j++)
          dst[j*16] = tobf16(acc[i][j][r] + ptn[j]);
      }
    }
    // pad rows 128..135 and 253..255 for this n-slice (const bf16(ptab))
    {
      int r = tid >> 5;            // 0..7
      int c4 = (tid & 31)*4;       // 0..124
      float4 pv = *(const float4*)&ptab[t*920 + n0 + c4];
      ushort4 v;
      v.x = tobf16(pv.x); v.y = tobf16(pv.y);
      v.z = tobf16(pv.z); v.w = tobf16(pv.w);
      *(ushort4*)&projh[(mdst + 128 + r)*NCC + n0 + c4] = v;
      if (r < 3)
        *(ushort4*)&projh[(mdst + 253 + r)*NCC + n0 + c4] = v;
    }
  } else {
    // scan_w: per (b,h) decay weights + const-tail sums
    float* wtot = (float*)smem;        // 4
    float* sred = (float*)smem + 4;    // 256
    int idx = bx - 896;                // 0..383
    int h = idx % NH, b = idx / NH;
    int lane = tid & 63, wid = tid >> 6;
    int tw = tid >> 5, q = tid & 31;
    float dtb = dt_bias[h];
    float negA = -expf(A_log[h]);
    float off = ptab[tw*920 + 896 + h] + dtb;
    float dtv[8], pre[8];
    float run = 0.f;
    if (q < 16){
      size_t rb = ((size_t)(b*TWIN + tw)*128 + q*8)*NH + h;
      #pragma unroll
      for (int i=0;i<8;i++){
        float dt = softplus_f(dtraw[rb + (size_t)i*NH] + off);
        run += dt * negA;
        dtv[i] = dt; pre[i] = run;
      }
    } else {
      float dt = softplus_f(off);
      #pragma unroll
      for (int i=0;i<8;i++){
        run += dt * negA;
        dtv[i] = dt; pre[i] = run;
      }
    }
    float v = run;
    #pragma unroll
    for (int o=1; o<64; o<<=1){
      float u = __shfl_up(v, o, 64);
      if (lane >= o) v += u;
    }
    if (lane == 63) wtot[wid] = v;
    __syncthreads();
    float base = 0.f, total = 0.f;
    #pragma unroll
    for (int w2=0; w2<4; w2++){
      float tv = wtot[w2];
      if (w2 < wid) base += tv;
      total += tv;
    }
    float excl = base + v - run;
    float ls = 0.f;
    size_t gb = (size_t)b*GLEN + tw*256 + q*8;
    #pragma unroll
    for (int i=0;i<8;i++){
      float w = expf(total - (excl + pre[i])) * dtv[i];
      if (q < 17) wbuf[(gb + i)*NH + h] = w;
      else ls += w;
    }
    sred[tid] = ls;
    __syncthreads();
    if (q == 17){
      float acc = ls;
      for (int r = 18; r < 32; r++) acc += sred[tw*32 + r];
      wsum[((size_t)b*TWIN + tw)*NH + h] = acc;
    }
  }
}

// Fused: fold+partial (1024 blocks: (bt,sub0..7), 17 positions each, exact 136
// coverage, all global loads hoisted to regs) + const-tail rows (128) +
// boundary vectors (112). 1264 blocks.
__global__ __launch_bounds__(256) void k_foldall(const unsigned short* __restrict__ projh,
    const float* __restrict__ conv_w, const float* __restrict__ conv_b,
    const float* __restrict__ wbuf, const float* __restrict__ ptab,
    const float* __restrict__ wsum, float* __restrict__ partial,
    float* __restrict__ cB, float* __restrict__ cbuf){
  __shared__ float smem[2800];   // 17*160 ybuf (A) / 2800 (B,C)
  int bx = blockIdx.x;
  int tid = threadIdx.x;
  if (bx < 1024){
    // fold+partial: block = (bt, sub); wave w folds positions w*4..w*4+3
    // (wave 3 also does position 16). All projh/wbuf reads batched upfront.
    int bt = bx >> 3, sub = bx & 7;
    int b = bt >> 3, t = bt & 7;
    int wave = tid >> 6, lane = tid & 63;
    int g0 = t*256 + sub*17;
    int wstart = wave*4;
    int gw = g0 + wstart;
    int cnt = (wave == 3) ? 5 : 4;
    size_t rbase = (size_t)b*GLEN;
    float* ybuf = smem;
    // ---- batched global loads: rows gw-3 .. gw+cnt-1 (packed bf16 pairs) ----
    unsigned rows[8][7];
    #pragma unroll
    for (int j=0;j<8;j++){
      if (j < cnt + 3){
        int ridx = g0 + wstart - 3 + j;      // within-batch row, may be <0 at t0/sub0/w0
        if (ridx >= 0){
          #pragma unroll
          for (int k=0;k<7;k++)
            rows[j][k] = *(const unsigned*)&projh[(rbase + ridx)*NCC + 2*lane + 128*k];
        } else {
          #pragma unroll
          for (int k=0;k<7;k++) rows[j][k] = 0u;
        }
      }
    }
    float wreg[5];
    #pragma unroll
    for (int i=0;i<5;i++)
      wreg[i] = (lane < NH && i < cnt) ? wbuf[(rbase + gw + i)*NH + lane] : 0.f;
    // conv weights/bias in regs
    float cb[7][2], cw[7][2][4];
    #pragma unroll
    for (int k=0;k<7;k++){
      int c = 2*lane + 128*k;
      float2 tb = *(const float2*)&conv_b[c];
      cb[k][0]=tb.x; cb[k][1]=tb.y;
      float4 w0 = *(const float4*)&conv_w[c*4];
      float4 w1 = *(const float4*)&conv_w[(c+1)*4];
      cw[k][0][0]=w0.x; cw[k][0][1]=w0.y; cw[k][0][2]=w0.z; cw[k][0][3]=w0.w;
      cw[k][1][0]=w1.x; cw[k][1][1]=w1.y; cw[k][1][2]=w1.z; cw[k][1][3]=w1.w;
    }
    #pragma unroll
    for (int i=0;i<5;i++){
      if (i < cnt){
        float py0=0.f, py1=0.f, b0v=0.f, b1v=0.f;
        #pragma unroll
        for (int k=0;k<7;k++){
          float a0 = cb[k][0] + bflo(rows[i][k])*cw[k][0][0]
                              + bflo(rows[i+1][k])*cw[k][0][1]
                              + bflo(rows[i+2][k])*cw[k][0][2]
                              + bflo(rows[i+3][k])*cw[k][0][3];
          float a1 = cb[k][1] + bfhi(rows[i][k])*cw[k][1][0]
                              + bfhi(rows[i+1][k])*cw[k][1][1]
                              + bfhi(rows[i+2][k])*cw[k][1][2]
                              + bfhi(rows[i+3][k])*cw[k][1][3];
          float s0 = silu_f(a0), s1 = silu_f(a1);
          if (k < 6){
            float wh_ = __shfl(wreg[i], (lane>>4) + 4*k, 64);
            py0 += wh_*s0; py1 += wh_*s1;
          } else { b0v = s0; b1v = s1; }
        }
        py0 += __shfl_xor(py0, 16, 64); py0 += __shfl_xor(py0, 32, 64);
        py1 += __shfl_xor(py1, 16, 64); py1 += __shfl_xor(py1, 32, 64);
        float* dst = ybuf + (wstart + i)*160;
        if (lane < 16) *(float2*)&dst[2*lane] = make_float2(py0, py1);
        *(float2*)&dst[32 + 2*lane] = make_float2(b0v, b1v);
      }
    }
    __syncthreads();
    int p0 = (tid >> 5)*4, n0 = (tid & 31)*4;
    float acc[4][4] = {};
    #pragma unroll 2
    for (int gi = 0; gi < 17; gi++){
      float4 yv = *(const float4*)&ybuf[gi*160 + p0];
      float4 bv = *(const float4*)&ybuf[gi*160 + 32 + n0];
      float ya[4] = {yv.x,yv.y,yv.z,yv.w};
      float ba[4] = {bv.x,bv.y,bv.z,bv.w};
      #pragma unroll
      for (int i=0;i<4;i++)
        #pragma unroll
        for (int j=0;j<4;j++)
          acc[i][j] += ya[i]*ba[j];
    }
    size_t pb = ((size_t)bt*8 + sub)*4096;
    #pragma unroll
    for (int i=0;i<4;i++)
      #pragma unroll
      for (int j=0;j<4;j++)
        partial[pb + (p0+i)*128 + n0+j] = acc[i][j];
  } else if (bx < 1152){
    float* Xc = smem;            // 896
    float* Ws = smem + 896;      // 24
    int idx = bx - 1024;
    int t = idx & 7, b = idx >> 3;
    for (int c = tid; c < NCC; c += 256){
      float4 w = *(const float4*)&conv_w[c*4];
      float sw = w.x + w.y + w.z + w.w;
      float a = conv_b[c] + frombf16(tobf16(ptab[t*920 + c])) * sw;
      Xc[c] = silu_f(a);
    }
    if (tid < NH) Ws[tid] = wsum[((size_t)b*TWIN + t)*NH + tid];
    __syncthreads();
    float* dst = cB + ((size_t)(b*TWIN + t))*160;
    if (tid < 32){
      float y = 0.f;
      #pragma unroll
      for (int h=0;h<NH;h++) y += Ws[h]*Xc[h*32 + tid];
      dst[tid] = y;
    } else if (tid < 160){
      dst[tid] = Xc[768 + tid - 32];
    }
  } else {
    float* xsw  = smem;          // 896
    float* xsg  = smem + 896;    // 896
    float* wv   = smem + 1792;   // 24
    float* bufw = smem + 1816;   // 480
    float* bufg = smem + 2296;   // 480
    int idx = bx - 1152;         // 0..111
    int b = idx / 7, t = idx % 7 + 1;
    size_t rbase = (size_t)b*GLEN;
    int g0 = t*256;
    for (int gi=0; gi<3; gi++){
      int g = g0 + gi;
      if (tid < NH) wv[tid] = wbuf[(rbase+g)*NH + tid];
      for (int c = tid; c < NCC; c += 256){
        float aw = conv_b[c], ag = conv_b[c];
        #pragma unroll
        for (int k=0;k<4;k++){
          int gp = g - 3 + k;
          // gp < g0: prev chunk pad row = const bf16(ptab[t-1])
          float pj = (gp >= g0) ? frombf16(projh[(rbase+gp)*NCC + c])
                                : frombf16(tobf16(ptab[(t-1)*920 + c]));
          float term = pj * conv_w[c*4+k];
          ag += term;
          if (gp >= g0) aw += term;
        }
        xsw[c] = silu_f(aw);
        xsg[c] = silu_f(ag);
      }
      __syncthreads();
      if (tid < 32){
        float yw = 0.f, yg = 0.f;
        #pragma unroll
        for (int h=0;h<NH;h++){ yw += wv[h]*xsw[h*32+tid]; yg += wv[h]*xsg[h*32+tid]; }
        bufw[gi*160 + tid] = yw;
        bufg[gi*160 + tid] = yg;
      } else if (tid < 160){
        bufw[gi*160 + tid] = xsw[768 + tid - 32];
        bufg[gi*160 + tid] = xsg[768 + tid - 32];
      }
      __syncthreads();
    }
    float* dst = cbuf + ((size_t)(b*TWIN + t))*960;
    for (int i = tid; i < 960; i += 256){
      int gi = i / 320, rem = i - gi*320;
      dst[i] = (rem < 160) ? bufw[gi*160 + rem] : bufg[gi*160 + rem - 160];
    }
  }
}

// Suffix-sum + const-tail + inline boundary deltas.
__global__ __launch_bounds__(256) void k_suffix(const float* __restrict__ partial,
    const float* __restrict__ cB, const float* __restrict__ cbuf,
    float* __restrict__ feat){
  int b = blockIdx.y;
  int e = blockIdx.x*256 + threadIdx.x;   // 0..4095
  int p = e >> 7, n = e & 127;
  float s = 0.f;
  for (int t = TWIN-1; t >= 0; t--){
    int bt = b*TWIN + t;
    size_t pb = (size_t)bt*8*4096;
    #pragma unroll
    for (int q=0;q<8;q++)
      s += partial[pb + (size_t)q*4096 + e];
    const float* cb_ = cB + (size_t)bt*160;
    s += cb_[p] * cb_[32 + n];
    float f = s;
    if (t > 0){
      const float* cw_ = cbuf + (size_t)bt*960;
      #pragma unroll
      for (int gi=0; gi<3; gi++){
        const float* rw = cw_ + gi*320;
        f += rw[p]*rw[32+n] - rw[160+p]*rw[192+n];
      }
    }
    feat[(size_t)bt*4096 + e] = f;
  }
}

// Classifier: 4x8 register-tiled, grid (32 bt-quads, 13 k-octs).
__global__ __launch_bounds__(256) void k_classifier(const float* __restrict__ feat,
    const float* __restrict__ cls_w, const float* __restrict__ cls_b,
    float* __restrict__ out){
  int bt0 = blockIdx.x*4;
  int k0  = blockIdx.y*8;
  int tid = threadIdx.x, wid = tid >> 6, lane = tid & 63;
  float acc[4][8] = {};
  int j0 = wid*1024;
  #pragma unroll
  for (int it = 0; it < 4; it++){
    int j = j0 + it*256 + lane*4;
    float4 f4[4], w4[8];
    #pragma unroll
    for (int i=0;i<4;i++) f4[i] = *(const float4*)(feat + (size_t)(bt0+i)*4096 + j);
    #pragma unroll
    for (int k=0;k<8;k++){
      int kr = k0 + k; kr = kr < 100 ? kr : 99;
      w4[k] = *(const float4*)(cls_w + (size_t)kr*4096 + j);
    }
    #pragma unroll
    for (int i=0;i<4;i++)
      #pragma unroll
      for (int k=0;k<8;k++)
        acc[i][k] += f4[i].x*w4[k].x + f4[i].y*w4[k].y
                   + f4[i].z*w4[k].z + f4[i].w*w4[k].w;
  }
  #pragma unroll
  for (int i=0;i<4;i++)
    #pragma unroll
    for (int k=0;k<8;k++)
      #pragma unroll
      for (int o=32; o>0; o>>=1)
        acc[i][k] += __shfl_down(acc[i][k], o, 64);
  __shared__ float part[4][32];
  if (lane == 0){
    #pragma unroll
    for (int i=0;i<4;i++)
      #pragma unroll
      for (int k=0;k<8;k++)
        part[wid][i*8+k] = acc[i][k];
  }
  __syncthreads();
  if (tid < 32){
    int i = tid >> 3, k = tid & 7;
    float s = part[0][tid] + part[1][tid] + part[2][tid] + part[3][tid];
    int kr = k0 + k;
    if (kr < 100) out[(size_t)(bt0+i)*100 + kr] = s + cls_b[kr];
  }
}

extern "C" void kernel_launch(void* const* d_in, const int* in_sizes, int n_in,
                              void* d_out, int out_size, void* d_ws, size_t ws_size,
                              hipStream_t stream){
  const float* inputs    = (const float*)d_in[0];
  const float* in_proj_w = (const float*)d_in[1];
  const float* conv_w    = (const float*)d_in[2];
  const float* conv_b    = (const float*)d_in[3];
  const float* dt_bias   = (const float*)d_in[4];
  const float* A_log     = (const float*)d_in[5];
  const float* cls_w     = (const float*)d_in[6];
  const float* cls_b     = (const float*)d_in[7];
  float* out = (float*)d_out;

  unsigned short* projh= (unsigned short*)d_ws;                 // MTOT*896 bf16
  float* dtraw         = (float*)(projh + (size_t)MTOT*NCC);    // NVALID*24 f32 (compact)
  float* wbuf          = dtraw + (size_t)NVALID*NH;             // MTOT*24 f32
  unsigned short* inh  = (unsigned short*)(wbuf + (size_t)MTOT*NH); // NVALID*192 bf16
  unsigned short* wh   = inh + (size_t)NVALID*DMODEL;           // NCC*192 bf16
  float* partial       = (float*)(wh + (size_t)NCC*DMODEL);     // 1024*4096 f32
  float* feat          = partial + (size_t)1024*4096;           // 128*4096 f32
  float* ptab          = feat + (size_t)128*4096;               // 8*920 f32
  float* wsum          = ptab + (size_t)8*920;                  // 128*24 f32
  float* cB            = wsum + (size_t)128*NH;                 // 128*160 f32
  float* cbuf          = cB + (size_t)128*160;                  // 128*960 f32
  size_t need = (size_t)((char*)(cbuf + (size_t)128*960) - (char*)d_ws);
  if (ws_size < need) return;

  k_build      <<<1172, 256, 0, stream>>>(inputs, in_proj_w, inh, wh, ptab, dtraw);
  k_gemmall    <<<1280, 256, 0, stream>>>(inh, wh, ptab, dtraw, dt_bias, A_log,
                                          projh, wbuf, wsum);
  k_foldall    <<<1264, 256, 0, stream>>>(projh, conv_w, conv_b, wbuf, ptab, wsum,
                                          partial, cB, cbuf);
  k_suffix     <<<dim3(16, BATCH), 256, 0, stream>>>(partial, cB, cbuf, feat);
  k_classifier <<<dim3(32, 13), 256, 0, stream>>>(feat, cls_w, cls_b, out);
}